// Round 3
// baseline (401.640 us; speedup 1.0000x reference)
//
#include <hip/hip_runtime.h>
#include <math.h>

#define P 45
#define N_ITER 20

// Pure-VALU cross-lane add via DPP (no LDS pipe).
template<int CTRL>
__device__ __forceinline__ float dpp_add(float x) {
    int xi = __builtin_bit_cast(int, x);
    int yi = __builtin_amdgcn_update_dpp(0, xi, CTRL, 0xF, 0xF, true);
    return x + __builtin_bit_cast(float, yi);
}

// Full wave64 sum, result broadcast to all lanes (readlane -> SGPR).
__device__ __forceinline__ float wave_sum_bcast(float x) {
    x = dpp_add<0x111>(x); // row_shr:1
    x = dpp_add<0x112>(x); // row_shr:2
    x = dpp_add<0x114>(x); // row_shr:4
    x = dpp_add<0x118>(x); // row_shr:8
    x = dpp_add<0x142>(x); // row_bcast:15
    x = dpp_add<0x143>(x); // row_bcast:31 -> lane 63 holds full sum
    int si = __builtin_amdgcn_readlane(__builtin_bit_cast(int, x), 63);
    return __builtin_bit_cast(float, si);
}

// (64, 4): cap at 4 waves/SIMD -> 128-VGPR budget, so the 45 pinned row
// registers never spill/remat. We have 32 waves/SIMD of supply; 4 resident
// is enough TLP for VALU-dominated work.
__global__ __launch_bounds__(64, 4) void drb_kernel(
    const float* __restrict__ sigma,
    const float* __restrict__ beta,
    const float* __restrict__ w_prev,
    const float* __restrict__ lls,
    const float* __restrict__ llt,
    float* __restrict__ out)
{
    const int b    = blockIdx.x;
    const int lane = threadIdx.x;
    const bool active = lane < P;
    const int  c   = active ? lane : (P - 1);  // clamp for lanes >= P

    const float lam_s  = expf(lls[0]);
    const float lam_t2 = 2.0f * expf(llt[0]);

    // sigma is bitwise symmetric (A A^T + 0.1 I): row i == column i.
    // Load lane i's "row" as column i -> lane-consecutive addresses, fully
    // coalesced: row[j] = sigma[b][j][i].
    const float* sp = sigma + (size_t)b * (P * P) + c;
    float row[P];
    #pragma unroll
    for (int j = 0; j < P; ++j) row[j] = sp[(size_t)j * P];
    // Pin each element in a VGPR (block rematerialization of the loads).
    #pragma unroll
    for (int j = 0; j < P; ++j) asm volatile("" : "+v"(row[j]));

    float bet = active ? beta[(size_t)b * P + lane]   : 0.0f;
    float wp  = active ? w_prev[(size_t)b * P + lane] : 0.0f;
    float wc  = active ? (float)(1.0 / 45.0)          : 0.0f;

    for (int it = 0; it < N_ITER; ++it) {
        const int wci = __builtin_bit_cast(int, wc);

        // Pass 1: broadcast all 45 w values (uniform -> SGPRs). Keeping this
        // separate from the FMAs gives the scheduler distance to hide the
        // VALU-writes-SGPR -> VALU-reads-SGPR hazard.
        float ws[P];
        #pragma unroll
        for (int j = 0; j < P; ++j)
            ws[j] = __builtin_bit_cast(float, __builtin_amdgcn_readlane(wci, j));

        // Pass 2: Sw_i = row_i . w, three independent chains of 15.
        float acc0 = 0.0f, acc1 = 0.0f, acc2 = 0.0f;
        #pragma unroll
        for (int j = 0; j < P; j += 3) {
            acc0 = fmaf(row[j],     ws[j],     acc0);
            acc1 = fmaf(row[j + 1], ws[j + 1], acc1);
            acc2 = fmaf(row[j + 2], ws[j + 2], acc2);
        }
        const float acc = (acc0 + acc1) + acc2;

        // gradient step
        float sgn = (wc > 0.0f) ? 1.0f : ((wc < 0.0f) ? -1.0f : 0.0f);
        float g   = 2.0f * acc - bet + lam_s * sgn + lam_t2 * (wc - wp);
        float wn  = wc - 0.05f * g;
        wn = active ? wn : 0.0f;   // lanes >= P contribute exact zeros

        // simplex projection: clip, renorm, clip, renorm
        wn = fminf(fmaxf(wn, 0.0f), 0.15f);
        float s = wave_sum_bcast(wn);
        wn *= __builtin_amdgcn_rcpf(s + 1e-8f);

        wn = fminf(fmaxf(wn, 0.0f), 0.15f);
        s = wave_sum_bcast(wn);
        wn *= __builtin_amdgcn_rcpf(s + 1e-8f);

        wc = wn;
    }

    if (active) out[(size_t)b * P + lane] = wc;
}

extern "C" void kernel_launch(void* const* d_in, const int* in_sizes, int n_in,
                              void* d_out, int out_size, void* d_ws, size_t ws_size,
                              hipStream_t stream) {
    const float* sigma  = (const float*)d_in[0];
    const float* beta   = (const float*)d_in[1];
    const float* w_prev = (const float*)d_in[2];
    const float* lls    = (const float*)d_in[3];
    const float* llt    = (const float*)d_in[4];
    float* out = (float*)d_out;

    const int B = in_sizes[1] / P;   // 32768
    drb_kernel<<<B, 64, 0, stream>>>(sigma, beta, w_prev, lls, llt, out);
}

// Round 4
// 397.458 us; speedup vs baseline: 1.0105x; 1.0105x over previous
//
#include <hip/hip_runtime.h>
#include <math.h>

#define P 45
#define N_ITER 20

// Pure-VALU cross-lane add via DPP (no LDS pipe).
template<int CTRL>
__device__ __forceinline__ float dpp_add(float x) {
    int xi = __builtin_bit_cast(int, x);
    int yi = __builtin_amdgcn_update_dpp(0, xi, CTRL, 0xF, 0xF, true);
    return x + __builtin_bit_cast(float, yi);
}

// Full wave64 sum, broadcast to all lanes via readlane -> SGPR.
__device__ __forceinline__ float wave_sum_bcast(float x) {
    x = dpp_add<0x111>(x); // row_shr:1
    x = dpp_add<0x112>(x); // row_shr:2
    x = dpp_add<0x114>(x); // row_shr:4
    x = dpp_add<0x118>(x); // row_shr:8
    x = dpp_add<0x142>(x); // row_bcast:15
    x = dpp_add<0x143>(x); // row_bcast:31 -> lane 63 holds full sum
    int si = __builtin_amdgcn_readlane(__builtin_bit_cast(int, x), 63);
    return __builtin_bit_cast(float, si);
}

__device__ __forceinline__ float clamp015(float x) {
    return __builtin_amdgcn_fmed3f(x, 0.0f, 0.15f);  // clamp(x, 0, 0.15)
}

// Default bounds: let the compiler pick its natural VGPR count / occupancy
// (R3's (64,4) cap regressed vs R2's default).
__global__ __launch_bounds__(64) void drb_kernel(
    const float* __restrict__ sigma,
    const float* __restrict__ beta,
    const float* __restrict__ w_prev,
    const float* __restrict__ lls,
    const float* __restrict__ llt,
    float* __restrict__ out)
{
    const int b    = blockIdx.x;
    const int lane = threadIdx.x;
    const bool active = lane < P;
    const int  cidx = active ? lane : (P - 1);

    const float lam_s  = expf(lls[0]);
    const float lam_t2 = 2.0f * expf(llt[0]);

    float bet = active ? beta[(size_t)b * P + lane]   : 0.0f;
    float wp  = active ? w_prev[(size_t)b * P + lane] : 0.0f;

    // sigma is bitwise symmetric (A A^T + 0.1 I): row i == column i.
    // Column loads -> lane-consecutive addresses, fully coalesced.
    // Lanes >= P get ZERO rows so they contribute exact zeros everywhere
    // (no per-iteration masking needed).
    const float* sp = sigma + (size_t)b * (P * P) + cidx;
    float row[P];
    #pragma unroll
    for (int j = 0; j < P; ++j) {
        float v = sp[(size_t)j * P];
        row[j] = active ? v : 0.0f;
    }
    #pragma unroll
    for (int j = 0; j < P; ++j) asm volatile("" : "+v"(row[j]));  // pin in VGPRs

    // Hoist loop-invariant part of the gradient: -beta - 2*lam_t*w_prev.
    const float base = -bet - lam_t2 * wp;

    // State: c = pre-scale weights (post-clip); true w = c * r where
    // r = 1/(sum(c)+eps) is computed at the TOP of the next iteration so its
    // reduction overlaps the broadcast+matvec instead of sitting exposed.
    float c = active ? (float)(1.0 / 45.0) : 0.0f;

    for (int it = 0; it < N_ITER; ++it) {
        const int ci = __builtin_bit_cast(int, c);

        // Broadcast all 45 c values into SGPRs.
        float cs[P];
        #pragma unroll
        for (int j = 0; j < P; ++j)
            cs[j] = __builtin_bit_cast(float, __builtin_amdgcn_readlane(ci, j));

        // Deferred-normalize reduction for the CURRENT weights; its DPP chain
        // and rcp hide under the readlane/FMA stream below.
        float s2 = wave_sum_bcast(c);
        float r  = __builtin_amdgcn_rcpf(s2 + 1e-8f);

        // acc_i = row_i . c  (three independent chains of 15)
        float acc0 = 0.0f, acc1 = 0.0f, acc2 = 0.0f;
        #pragma unroll
        for (int j = 0; j < P; j += 3) {
            acc0 = fmaf(row[j],     cs[j],     acc0);
            acc1 = fmaf(row[j + 1], cs[j + 1], acc1);
            acc2 = fmaf(row[j + 2], cs[j + 2], acc2);
        }
        const float acc = (acc0 + acc1) + acc2;

        // w_i = c_i * r;  Sw_i = r * acc
        const float t  = c * r;
        const float u  = r + r;                       // 2r
        float g = fmaf(lam_t2, t, base);              // 2*lam_t*(w - wp) - beta (partial)
        g += (c > 0.0f) ? lam_s : 0.0f;               // lam_s * sign(w)
        g  = fmaf(u, acc, g);                         // + 2*Sw
        const float x = fmaf(-0.05f, g, t);           // w - step*grad

        // projection: clip, renorm, clip; final renorm deferred to next iter.
        const float a  = clamp015(x);
        const float s1 = wave_sum_bcast(a);
        const float r1 = __builtin_amdgcn_rcpf(s1 + 1e-8f);
        c = clamp015(a * r1);
    }

    // Epilogue: apply the final deferred normalize.
    const float sf = wave_sum_bcast(c);
    const float rf = __builtin_amdgcn_rcpf(sf + 1e-8f);
    if (active) out[(size_t)b * P + lane] = c * rf;
}

extern "C" void kernel_launch(void* const* d_in, const int* in_sizes, int n_in,
                              void* d_out, int out_size, void* d_ws, size_t ws_size,
                              hipStream_t stream) {
    const float* sigma  = (const float*)d_in[0];
    const float* beta   = (const float*)d_in[1];
    const float* w_prev = (const float*)d_in[2];
    const float* lls    = (const float*)d_in[3];
    const float* llt    = (const float*)d_in[4];
    float* out = (float*)d_out;

    const int B = in_sizes[1] / P;   // 32768
    drb_kernel<<<B, 64, 0, stream>>>(sigma, beta, w_prev, lls, llt, out);
}

// Round 5
// 395.775 us; speedup vs baseline: 1.0148x; 1.0043x over previous
//
#include <hip/hip_runtime.h>
#include <math.h>

#define P 45
#define N_ITER 20

// Pure-VALU cross-lane add via DPP (no LDS pipe).
template<int CTRL>
__device__ __forceinline__ float dpp_add(float x) {
    int xi = __builtin_bit_cast(int, x);
    int yi = __builtin_amdgcn_update_dpp(0, xi, CTRL, 0xF, 0xF, true);
    return x + __builtin_bit_cast(float, yi);
}

// Full wave64 sum, broadcast to all lanes via readlane -> SGPR.
__device__ __forceinline__ float wave_sum_bcast(float x) {
    x = dpp_add<0x111>(x); // row_shr:1
    x = dpp_add<0x112>(x); // row_shr:2
    x = dpp_add<0x114>(x); // row_shr:4
    x = dpp_add<0x118>(x); // row_shr:8
    x = dpp_add<0x142>(x); // row_bcast:15
    x = dpp_add<0x143>(x); // row_bcast:31 -> lane 63 holds full sum
    int si = __builtin_amdgcn_readlane(__builtin_bit_cast(int, x), 63);
    return __builtin_bit_cast(float, si);
}

__device__ __forceinline__ float clamp015(float x) {
    return __builtin_amdgcn_fmed3f(x, 0.0f, 0.15f);
}

// (64, 6): 6 waves/SIMD -> 85-VGPR budget. Working set is ~60-65 VGPRs
// (45 pinned rows + temps; w-broadcast lives in SGPRs), so rows stay
// register-resident AND we get 6 waves/SIMD of TLP to hide the FMA/DPP
// dependency chains. R3's (64,4) had the budget but too little TLP;
// R2/R4's default may have demoted the rows. This is the untested corner.
__global__ __launch_bounds__(64, 6) void drb_kernel(
    const float* __restrict__ sigma,
    const float* __restrict__ beta,
    const float* __restrict__ w_prev,
    const float* __restrict__ lls,
    const float* __restrict__ llt,
    float* __restrict__ out)
{
    const int b    = blockIdx.x;
    const int lane = threadIdx.x;
    const bool active = lane < P;

    const float lam_s  = expf(lls[0]);
    const float lam_t2 = 2.0f * expf(llt[0]);

    // Loop-invariant gradient part: -beta - 2*lam_t*w_prev (wp dies here).
    float base = 0.0f;
    if (active) {
        const float bet = beta[(size_t)b * P + lane];
        const float wp  = w_prev[(size_t)b * P + lane];
        base = -bet - lam_t2 * wp;
    }

    // sigma is bitwise symmetric (A A^T + 0.1 I): row i == column i.
    // Column loads -> lane-consecutive, fully coalesced. Lanes >= P get
    // zero rows so they contribute exact zeros with no per-iter masking.
    {
    }
    const int cidx = active ? lane : (P - 1);
    const float* sp = sigma + (size_t)b * (P * P) + cidx;
    float row[P];
    #pragma unroll
    for (int j = 0; j < P; ++j) {
        float v = sp[(size_t)j * P];
        row[j] = active ? v : 0.0f;
    }
    #pragma unroll
    for (int j = 0; j < P; ++j) asm volatile("" : "+v"(row[j]));  // pin

    // State: c = pre-scale weights (post-clip); true w = c * r with
    // r = 1/(sum(c)+eps) computed at the TOP of the next iteration so the
    // reduction overlaps the broadcast/matvec stream.
    float c = active ? (float)(1.0 / 45.0) : 0.0f;

    for (int it = 0; it < N_ITER; ++it) {
        const int ci = __builtin_bit_cast(int, c);

        // Broadcast all 45 c values into SGPRs.
        float cs[P];
        #pragma unroll
        for (int j = 0; j < P; ++j)
            cs[j] = __builtin_bit_cast(float, __builtin_amdgcn_readlane(ci, j));

        // Deferred-normalize reduction for current weights (hides under the
        // readlane/FMA stream).
        const float s2 = wave_sum_bcast(c);
        const float r  = __builtin_amdgcn_rcpf(s2 + 1e-8f);

        // acc_i = row_i . c  (three independent chains of 15)
        float acc0 = 0.0f, acc1 = 0.0f, acc2 = 0.0f;
        #pragma unroll
        for (int j = 0; j < P; j += 3) {
            acc0 = fmaf(row[j],     cs[j],     acc0);
            acc1 = fmaf(row[j + 1], cs[j + 1], acc1);
            acc2 = fmaf(row[j + 2], cs[j + 2], acc2);
        }
        const float acc = (acc0 + acc1) + acc2;

        // w_i = c_i * r;  Sw_i = r * acc
        const float t = c * r;
        float g = fmaf(lam_t2, t, base);
        g += (c > 0.0f) ? lam_s : 0.0f;
        g  = fmaf(r + r, acc, g);
        const float x = fmaf(-0.05f, g, t);

        // projection: clip, renorm, clip; final renorm deferred.
        const float a  = clamp015(x);
        const float s1 = wave_sum_bcast(a);
        const float r1 = __builtin_amdgcn_rcpf(s1 + 1e-8f);
        c = clamp015(a * r1);
    }

    // Epilogue: apply the final deferred normalize.
    const float sf = wave_sum_bcast(c);
    const float rf = __builtin_amdgcn_rcpf(sf + 1e-8f);
    if (active) out[(size_t)b * P + lane] = c * rf;
}

extern "C" void kernel_launch(void* const* d_in, const int* in_sizes, int n_in,
                              void* d_out, int out_size, void* d_ws, size_t ws_size,
                              hipStream_t stream) {
    const float* sigma  = (const float*)d_in[0];
    const float* beta   = (const float*)d_in[1];
    const float* w_prev = (const float*)d_in[2];
    const float* lls    = (const float*)d_in[3];
    const float* llt    = (const float*)d_in[4];
    float* out = (float*)d_out;

    const int B = in_sizes[1] / P;   // 32768
    drb_kernel<<<B, 64, 0, stream>>>(sigma, beta, w_prev, lls, llt, out);
}

// Round 6
// 377.161 us; speedup vs baseline: 1.0649x; 1.0494x over previous
//
#include <hip/hip_runtime.h>
#include <math.h>

#define P 45
#define N_ITER 20

typedef float v2f __attribute__((ext_vector_type(2)));
typedef float v4f __attribute__((ext_vector_type(4)));

// Pure-VALU cross-lane add via DPP (no LDS pipe).
template<int CTRL>
__device__ __forceinline__ float dpp_add(float x) {
    int xi = __builtin_bit_cast(int, x);
    int yi = __builtin_amdgcn_update_dpp(0, xi, CTRL, 0xF, 0xF, true);
    return x + __builtin_bit_cast(float, yi);
}

// Full wave64 sum, broadcast to all lanes via readlane -> SGPR.
__device__ __forceinline__ float wave_sum_bcast(float x) {
    x = dpp_add<0x111>(x); // row_shr:1
    x = dpp_add<0x112>(x); // row_shr:2
    x = dpp_add<0x114>(x); // row_shr:4
    x = dpp_add<0x118>(x); // row_shr:8
    x = dpp_add<0x142>(x); // row_bcast:15
    x = dpp_add<0x143>(x); // row_bcast:31 -> lane 63 holds full sum
    int si = __builtin_amdgcn_readlane(__builtin_bit_cast(int, x), 63);
    return __builtin_bit_cast(float, si);
}

__device__ __forceinline__ float clamp015(float x) {
    return __builtin_amdgcn_fmed3f(x, 0.0f, 0.15f);
}

__global__ __launch_bounds__(64) void drb_kernel(
    const float* __restrict__ sigma,
    const float* __restrict__ beta,
    const float* __restrict__ w_prev,
    const float* __restrict__ lls,
    const float* __restrict__ llt,
    float* __restrict__ out)
{
    const int b    = blockIdx.x;
    const int lane = threadIdx.x;
    const bool active = lane < P;

    const float lam_s  = expf(lls[0]);
    const float lam_t2 = 2.0f * expf(llt[0]);

    // Loop-invariant gradient part: -beta - 2*lam_t*w_prev.
    float base = 0.0f;
    if (active) {
        base = -beta[(size_t)b * P + lane]
               - lam_t2 * w_prev[(size_t)b * P + lane];
    }

    // sigma is bitwise symmetric: row i == column i -> coalesced column loads.
    // Lanes > P: zero rows (exact-zero contributions, no per-iter masking).
    // Lane P (45) gets an all-ONES row: its matvec output = sum(c), which
    // replaces a whole 7-instr DPP reduction with one readlane.
    const int cidx = active ? lane : 0;
    const float* sp = sigma + (size_t)b * (P * P) + cidx;
    float rv[P + 1];
    #pragma unroll
    for (int j = 0; j < P; ++j) {
        float v = sp[(size_t)j * P];
        rv[j] = active ? v : 0.0f;
    }
    rv[P] = 0.0f;
    const bool ones = (lane == P);
    v2f row2[23];
    #pragma unroll
    for (int k = 0; k < 23; ++k) {
        float lo = ones ? 1.0f : rv[2 * k];
        float hi = (2 * k + 1 < P) ? (ones ? 1.0f : rv[2 * k + 1]) : 0.0f;
        v2f t; t.x = lo; t.y = hi;
        row2[k] = t;
    }
    #pragma unroll
    for (int k = 0; k < 23; ++k) asm volatile("" : "+v"(row2[k]));  // pin

    // Double-buffered 64-float w slots (kills write-after-read across iters).
    __shared__ __align__(16) float sh[128];

    // State: c = pre-scale weights; true w = c * r, r = rcp(sum(c)+eps)
    // obtained for free from the ones-row matvec output.
    float c = active ? (float)(1.0 / 45.0) : 0.0f;

    for (int it = 0; it < N_ITER; ++it) {
        float* shb = sh + ((it & 1) << 6);
        shb[lane] = c;               // lanes >= P publish exact zeros
        __syncthreads();             // 1 wave: cheap; orders write -> reads
        const v4f* shv = (const v4f*)shb;

        // acc_i = row_i . c via packed-fp32 FMAs; broadcast w read as b128.
        v2f acc0; acc0.x = 0.0f; acc0.y = 0.0f;
        v2f acc1 = acc0, acc2 = acc0;
        #pragma unroll
        for (int k = 0; k < 11; ++k) {
            v4f q = shv[k];
            v2f lo; lo.x = q.x; lo.y = q.y;
            v2f hi; hi.x = q.z; hi.y = q.w;
            acc0 = __builtin_elementwise_fma(row2[2 * k],     lo, acc0);
            acc1 = __builtin_elementwise_fma(row2[2 * k + 1], hi, acc1);
        }
        {
            v4f q = shv[11];
            v2f lo; lo.x = q.x; lo.y = q.y;   // floats 44,45 (45 is zero slot)
            acc2 = __builtin_elementwise_fma(row2[22], lo, acc2);
        }
        v2f am = acc0 + acc1;
        am = am + acc2;
        const float acc = am.x + am.y;

        // sum(c) falls out of lane 45's ones-row dot product.
        const float s2 = __builtin_bit_cast(float,
            __builtin_amdgcn_readlane(__builtin_bit_cast(int, acc), P));
        const float r = __builtin_amdgcn_rcpf(s2 + 1e-8f);

        // w_i = c_i * r;  Sw_i = r * acc
        const float t = c * r;
        float g = fmaf(lam_t2, t, base);
        g += (c > 0.0f) ? lam_s : 0.0f;
        g = fmaf(r + r, acc, g);
        const float x = fmaf(-0.05f, g, t);

        // projection: clip, renorm, clip; final renorm deferred.
        const float a  = clamp015(x);
        const float s1 = wave_sum_bcast(a);
        const float r1 = __builtin_amdgcn_rcpf(s1 + 1e-8f);
        c = clamp015(a * r1);
        // lane 45: acc = sum(c) -> x < 0 -> a = 0 -> stays exactly 0. Lanes
        // 46-63: everything 0 -> stay 0. So slots 45..47 read above are 0.
    }

    // Epilogue: apply the final deferred normalize.
    const float sf = wave_sum_bcast(c);
    const float rf = __builtin_amdgcn_rcpf(sf + 1e-8f);
    if (active) out[(size_t)b * P + lane] = c * rf;
}

extern "C" void kernel_launch(void* const* d_in, const int* in_sizes, int n_in,
                              void* d_out, int out_size, void* d_ws, size_t ws_size,
                              hipStream_t stream) {
    const float* sigma  = (const float*)d_in[0];
    const float* beta   = (const float*)d_in[1];
    const float* w_prev = (const float*)d_in[2];
    const float* lls    = (const float*)d_in[3];
    const float* llt    = (const float*)d_in[4];
    float* out = (float*)d_out;

    const int B = in_sizes[1] / P;   // 32768
    drb_kernel<<<B, 64, 0, stream>>>(sigma, beta, w_prev, lls, llt, out);
}